// Round 2
// baseline (115.081 us; speedup 1.0000x reference)
//
#include <hip/hip_runtime.h>
#include <hip/hip_bf16.h>

#define BATCH 8192
#define NF 512
#define NL 1024
#define ATOMS 513

typedef float float4v __attribute__((ext_vector_type(4)));
typedef short short8 __attribute__((ext_vector_type(8)));

// fp32 -> bf16 bits, round-to-nearest-even
__device__ __forceinline__ unsigned short f2bf(float f) {
    union { float f; unsigned int u; } cv; cv.f = f;
    unsigned int u = cv.u;
    u += 0x7fffu + ((u >> 16) & 1u);
    return (unsigned short)(u >> 16);
}

// ---------------- Kernel 0: X fp32 -> bf16 (memory-bound, ~4 us) ----------------
__global__ void convert_kernel(const float* __restrict__ X,
                               unsigned short* __restrict__ Xb) {
    size_t i = ((size_t)blockIdx.x * 256 + threadIdx.x) * 8;
    float4v x0 = *reinterpret_cast<const float4v*>(X + i);
    float4v x1 = *reinterpret_cast<const float4v*>(X + i + 4);
    short8 a;
    a[0] = (short)f2bf(x0[0]); a[1] = (short)f2bf(x0[1]);
    a[2] = (short)f2bf(x0[2]); a[3] = (short)f2bf(x0[3]);
    a[4] = (short)f2bf(x1[0]); a[5] = (short)f2bf(x1[1]);
    a[6] = (short)f2bf(x1[2]); a[7] = (short)f2bf(x1[3]);
    *reinterpret_cast<short8*>(Xb + i) = a;
}

// ---------------- Kernel 1: per-leaf softmax over 513 atoms ----------------
// Wb[l][k] = bf16(softmax[l][k+1]) (k contiguous), bias[l] = softmax[l][0].
__global__ void softmax_kernel(const float* __restrict__ logits,
                               unsigned short* __restrict__ Wb,
                               float* __restrict__ bias) {
    int l = blockIdx.x;
    int t = threadIdx.x;
    int wave = t >> 6, lane = t & 63;
    const float* row = logits + (size_t)l * ATOMS;
    float v0 = row[t];
    float v1 = row[t + 256];
    float v2 = (t == 0) ? row[512] : -1e30f;

    __shared__ float red[8];
    float m = fmaxf(fmaxf(v0, v1), v2);
#pragma unroll
    for (int o = 32; o > 0; o >>= 1) m = fmaxf(m, __shfl_xor(m, o, 64));
    if (lane == 0) red[wave] = m;
    __syncthreads();
    float mx = fmaxf(fmaxf(red[0], red[1]), fmaxf(red[2], red[3]));

    float e0 = __expf(v0 - mx);
    float e1 = __expf(v1 - mx);
    float e2 = (t == 0) ? __expf(v2 - mx) : 0.f;
    float s = e0 + e1 + e2;
#pragma unroll
    for (int o = 32; o > 0; o >>= 1) s += __shfl_xor(s, o, 64);
    if (lane == 0) red[4 + wave] = s;
    __syncthreads();
    float inv = 1.f / (red[4] + red[5] + red[6] + red[7]);

    unsigned short* wrow = Wb + (size_t)l * NF;
    if (t == 0) {
        bias[l] = e0 * inv;            // atom 0 (constant 1)
        wrow[511] = f2bf(e2 * inv);    // atom 512 -> k=511
    } else {
        wrow[t - 1] = f2bf(e0 * inv);  // atoms 1..255 -> k=0..254
    }
    wrow[t + 255] = f2bf(e1 * inv);    // atoms 256..511 -> k=255..510
}

// ---------------- Kernel 2: bf16-MFMA GEMM + partial sum-exp ----------------
// Grid: 1024 blocks = (8192/32 row groups) x (1024/256 leaf chunks).
// Block: 32 rows, 4 waves; wave owns 64 leaves (4 n-tiles of 16).
// mfma_f32_16x16x32_bf16: A[m=lane&15][k=quad*8+j], B[k][n=lane&15],
// C/D: col=lane&15, row=quad*4+r.
__global__ __launch_bounds__(256, 4)
void gemm_lse_kernel(const unsigned short* __restrict__ Xb,
                     const unsigned short* __restrict__ Wb,
                     const float* __restrict__ bias,
                     float* __restrict__ partial) {
    int tid  = threadIdx.x;
    int wave = tid >> 6;
    int lane = tid & 63;
    int quad = lane >> 4;
    int l16  = lane & 15;
    int rg   = blockIdx.x >> 2;       // row group (adjacent blocks share X rows -> L2)
    int nb   = blockIdx.x & 3;        // leaf chunk
    int R0   = rg * 32;
    int nBase = nb * 256 + wave * 64;

    float4v acc[4][2];
#pragma unroll
    for (int nt = 0; nt < 4; ++nt)
#pragma unroll
        for (int mt = 0; mt < 2; ++mt)
            acc[nt][mt] = (float4v){0.f, 0.f, 0.f, 0.f};

    for (int kt = 0; kt < 16; ++kt) {
        int kb = kt * 32 + quad * 8;
        short8 afrag[2];
#pragma unroll
        for (int mt = 0; mt < 2; ++mt)
            afrag[mt] = *reinterpret_cast<const short8*>(
                Xb + (size_t)(R0 + mt * 16 + l16) * NF + kb);
#pragma unroll
        for (int nt = 0; nt < 4; ++nt) {
            short8 b = *reinterpret_cast<const short8*>(
                Wb + (size_t)(nBase + nt * 16 + l16) * NF + kb);
            acc[nt][0] = __builtin_amdgcn_mfma_f32_16x16x32_bf16(afrag[0], b, acc[nt][0], 0, 0, 0);
            acc[nt][1] = __builtin_amdgcn_mfma_f32_16x16x32_bf16(afrag[1], b, acc[nt][1], 0, 0, 0);
        }
    }

    // partial[mt][r] = sum over this wave's 64 leaves of exp(c + bias)
    float psum[2][4];
#pragma unroll
    for (int mt = 0; mt < 2; ++mt)
#pragma unroll
        for (int r = 0; r < 4; ++r) psum[mt][r] = 0.f;

#pragma unroll
    for (int nt = 0; nt < 4; ++nt) {
        float bl = bias[nBase + nt * 16 + l16];
#pragma unroll
        for (int mt = 0; mt < 2; ++mt)
#pragma unroll
            for (int r = 0; r < 4; ++r)
                psum[mt][r] += __expf(acc[nt][mt][r] + bl);
    }

    // reduce across the 16 columns (xor masks < 16 stay within the quad group)
#pragma unroll
    for (int m = 1; m < 16; m <<= 1)
#pragma unroll
        for (int mt = 0; mt < 2; ++mt)
#pragma unroll
            for (int r = 0; r < 4; ++r)
                psum[mt][r] += __shfl_xor(psum[mt][r], m, 64);

    __shared__ float sums[4][32];
    if (l16 == 0) {
#pragma unroll
        for (int mt = 0; mt < 2; ++mt)
#pragma unroll
            for (int r = 0; r < 4; ++r)
                sums[wave][mt * 16 + quad * 4 + r] = psum[mt][r];
    }
    __syncthreads();
    if (tid < 32) {
        float s = sums[0][tid] + sums[1][tid] + sums[2][tid] + sums[3][tid];
        partial[(size_t)nb * BATCH + R0 + tid] = s;
    }
}

// ---------------- Kernel 3: combine 4 leaf-chunk partials, take log ----------------
__global__ void combine_kernel(const float* __restrict__ partial,
                               float* __restrict__ out) {
    int i = blockIdx.x * 256 + threadIdx.x;
    float s = partial[i] + partial[BATCH + i] + partial[2 * BATCH + i] + partial[3 * BATCH + i];
    out[i] = logf(s);
}

extern "C" void kernel_launch(void* const* d_in, const int* in_sizes, int n_in,
                              void* d_out, int out_size, void* d_ws, size_t ws_size,
                              hipStream_t stream) {
    const float* X      = (const float*)d_in[0];   // (8192, 512) fp32
    const float* logits = (const float*)d_in[1];   // (1024, 513) fp32
    float* out = (float*)d_out;                    // (8192,) fp32

    char* ws = (char*)d_ws;
    unsigned short* Xb   = (unsigned short*)ws;                          // 8 MB
    unsigned short* Wb   = (unsigned short*)(ws + (size_t)BATCH * NF * 2);       // 1 MB
    float*          bias = (float*)(ws + (size_t)BATCH * NF * 2 + (size_t)NL * NF * 2);
    float*          part = (float*)(ws + (size_t)BATCH * NF * 2 + (size_t)NL * NF * 2 + NL * 4);

    convert_kernel<<<(BATCH * NF) / (256 * 8), 256, 0, stream>>>(X, Xb);
    softmax_kernel<<<NL, 256, 0, stream>>>(logits, Wb, bias);
    gemm_lse_kernel<<<(BATCH / 32) * 4, 256, 0, stream>>>(Xb, Wb, bias, part);
    combine_kernel<<<BATCH / 256, 256, 0, stream>>>(part, out);
}

// Round 3
// 86.730 us; speedup vs baseline: 1.3269x; 1.3269x over previous
//
#include <hip/hip_runtime.h>
#include <hip/hip_bf16.h>

#define BATCH 8192
#define NF 512
#define NL 1024
#define ATOMS 513

typedef float float4v __attribute__((ext_vector_type(4)));
typedef short short8 __attribute__((ext_vector_type(8)));

// fp32 -> bf16 bits, round-to-nearest-even
__device__ __forceinline__ unsigned short f2bf(float f) {
    union { float f; unsigned int u; } cv; cv.f = f;
    unsigned int u = cv.u;
    u += 0x7fffu + ((u >> 16) & 1u);
    return (unsigned short)(u >> 16);
}

// async 16B/lane global->LDS: lane i lands at ldsbase + i*16 (wave-uniform base)
__device__ __forceinline__ void load_lds16(const unsigned short* g, unsigned short* ldsbase) {
    __builtin_amdgcn_global_load_lds(
        (const __attribute__((address_space(1))) unsigned int*)g,
        (__attribute__((address_space(3))) unsigned int*)ldsbase,
        16, 0, 0);
}

// ---------------- Kernel 0: X fp32 -> bf16 ----------------
__global__ void convert_kernel(const float* __restrict__ X,
                               unsigned short* __restrict__ Xb) {
    size_t i = ((size_t)blockIdx.x * 256 + threadIdx.x) * 8;
    float4v x0 = *reinterpret_cast<const float4v*>(X + i);
    float4v x1 = *reinterpret_cast<const float4v*>(X + i + 4);
    short8 a;
    a[0] = (short)f2bf(x0[0]); a[1] = (short)f2bf(x0[1]);
    a[2] = (short)f2bf(x0[2]); a[3] = (short)f2bf(x0[3]);
    a[4] = (short)f2bf(x1[0]); a[5] = (short)f2bf(x1[1]);
    a[6] = (short)f2bf(x1[2]); a[7] = (short)f2bf(x1[3]);
    *reinterpret_cast<short8*>(Xb + i) = a;
}

// ---------------- Kernel 1: per-leaf softmax over 513 atoms ----------------
__global__ void softmax_kernel(const float* __restrict__ logits,
                               unsigned short* __restrict__ Wb,
                               float* __restrict__ bias) {
    int l = blockIdx.x;
    int t = threadIdx.x;
    int wave = t >> 6, lane = t & 63;
    const float* row = logits + (size_t)l * ATOMS;
    float v0 = row[t];
    float v1 = row[t + 256];
    float v2 = (t == 0) ? row[512] : -1e30f;

    __shared__ float red[8];
    float m = fmaxf(fmaxf(v0, v1), v2);
#pragma unroll
    for (int o = 32; o > 0; o >>= 1) m = fmaxf(m, __shfl_xor(m, o, 64));
    if (lane == 0) red[wave] = m;
    __syncthreads();
    float mx = fmaxf(fmaxf(red[0], red[1]), fmaxf(red[2], red[3]));

    float e0 = __expf(v0 - mx);
    float e1 = __expf(v1 - mx);
    float e2 = (t == 0) ? __expf(v2 - mx) : 0.f;
    float s = e0 + e1 + e2;
#pragma unroll
    for (int o = 32; o > 0; o >>= 1) s += __shfl_xor(s, o, 64);
    if (lane == 0) red[4 + wave] = s;
    __syncthreads();
    float inv = 1.f / (red[4] + red[5] + red[6] + red[7]);

    unsigned short* wrow = Wb + (size_t)l * NF;
    if (t == 0) {
        bias[l] = e0 * inv;
        wrow[511] = f2bf(e2 * inv);
    } else {
        wrow[t - 1] = f2bf(e0 * inv);
    }
    wrow[t + 255] = f2bf(e1 * inv);
}

// ---------------- Kernel 2: m97-style 128x128 MFMA GEMM + partial sum-exp ----------------
// Grid: 512 blocks = 64 row-tiles x 8 leaf-tiles. 4 waves in 2x2; wave = 64x64.
// LDS: As[128][32] / Bs[128][32] bf16 row-major (64B rows), staged via
// global_load_lds width=16 (lane i -> base + i*16: row = i/4, 16B chunk i%4).
__global__ __launch_bounds__(256, 2)
void gemm_lse_kernel(const unsigned short* __restrict__ Xb,
                     const unsigned short* __restrict__ Wb,
                     const float* __restrict__ bias,
                     float* __restrict__ partial) {
    __shared__ unsigned short As[128 * 32];
    __shared__ unsigned short Bs[128 * 32];
    __shared__ float sums[2][128];

    int tid  = threadIdx.x;
    int wave = tid >> 6;
    int lane = tid & 63;
    int quad = lane >> 4;
    int l16  = lane & 15;
    int wr = wave >> 1;      // wave row (0..1) -> 64 batch rows
    int wc = wave & 1;       // wave col (0..1) -> 64 leaves

    int mb = blockIdx.x >> 3;
    int nb = blockIdx.x & 7;
    int R0 = mb * 128;
    int N0 = nb * 128;

    // staging: this wave stages rows [wave*32, wave*32+32) of both tiles
    int srow = wave * 32 + (lane >> 2);
    int selem = (lane & 3) * 8;

    float4v acc[4][4];
#pragma unroll
    for (int mt = 0; mt < 4; ++mt)
#pragma unroll
        for (int nt = 0; nt < 4; ++nt)
            acc[mt][nt] = (float4v){0.f, 0.f, 0.f, 0.f};

    for (int kt = 0; kt < 16; ++kt) {
        int kb = kt * 32;
        const unsigned short* ga = Xb + (size_t)(R0 + srow) * NF + kb + selem;
        const unsigned short* gb = Wb + (size_t)(N0 + srow) * NF + kb + selem;
        load_lds16(ga,            &As[(wave * 32) * 32]);
        load_lds16(ga + 16 * NF,  &As[(wave * 32 + 16) * 32]);
        load_lds16(gb,            &Bs[(wave * 32) * 32]);
        load_lds16(gb + 16 * NF,  &Bs[(wave * 32 + 16) * 32]);
        __syncthreads();   // drains vmcnt -> LDS tiles ready

        short8 af[4], bfr[4];
#pragma unroll
        for (int mt = 0; mt < 4; ++mt)
            af[mt] = *reinterpret_cast<const short8*>(
                &As[(wr * 64 + mt * 16 + l16) * 32 + quad * 8]);
#pragma unroll
        for (int nt = 0; nt < 4; ++nt)
            bfr[nt] = *reinterpret_cast<const short8*>(
                &Bs[(wc * 64 + nt * 16 + l16) * 32 + quad * 8]);

#pragma unroll
        for (int mt = 0; mt < 4; ++mt)
#pragma unroll
            for (int nt = 0; nt < 4; ++nt)
                acc[mt][nt] = __builtin_amdgcn_mfma_f32_16x16x32_bf16(
                    af[mt], bfr[nt], acc[mt][nt], 0, 0, 0);
        __syncthreads();   // protect LDS before next-kt restage
    }

    // Epilogue: sum exp(c + bias) over this wave's 64 leaves per C-row
    float ps[4][4];
#pragma unroll
    for (int mt = 0; mt < 4; ++mt)
#pragma unroll
        for (int r = 0; r < 4; ++r) ps[mt][r] = 0.f;

#pragma unroll
    for (int nt = 0; nt < 4; ++nt) {
        float bl = bias[N0 + wc * 64 + nt * 16 + l16];
#pragma unroll
        for (int mt = 0; mt < 4; ++mt)
#pragma unroll
            for (int r = 0; r < 4; ++r)
                ps[mt][r] += __expf(acc[mt][nt][r] + bl);
    }

    // reduce across the 16 columns (xor masks < 16 stay within quad group)
#pragma unroll
    for (int m = 1; m < 16; m <<= 1)
#pragma unroll
        for (int mt = 0; mt < 4; ++mt)
#pragma unroll
            for (int r = 0; r < 4; ++r)
                ps[mt][r] += __shfl_xor(ps[mt][r], m, 64);

    if (l16 == 0) {
#pragma unroll
        for (int mt = 0; mt < 4; ++mt)
#pragma unroll
            for (int r = 0; r < 4; ++r)
                sums[wc][wr * 64 + mt * 16 + quad * 4 + r] = ps[mt][r];
    }
    __syncthreads();
    if (tid < 128)
        partial[(size_t)nb * BATCH + R0 + tid] = sums[0][tid] + sums[1][tid];
}

// ---------------- Kernel 3: combine 8 leaf-panel partials, take log ----------------
__global__ void combine_kernel(const float* __restrict__ partial,
                               float* __restrict__ out) {
    int i = blockIdx.x * 256 + threadIdx.x;
    float s = 0.f;
#pragma unroll
    for (int c = 0; c < 8; ++c) s += partial[(size_t)c * BATCH + i];
    out[i] = logf(s);
}

extern "C" void kernel_launch(void* const* d_in, const int* in_sizes, int n_in,
                              void* d_out, int out_size, void* d_ws, size_t ws_size,
                              hipStream_t stream) {
    const float* X      = (const float*)d_in[0];   // (8192, 512) fp32
    const float* logits = (const float*)d_in[1];   // (1024, 513) fp32
    float* out = (float*)d_out;                    // (8192,) fp32

    char* ws = (char*)d_ws;
    unsigned short* Xb   = (unsigned short*)ws;                                   // 8 MB
    unsigned short* Wb   = (unsigned short*)(ws + (size_t)BATCH * NF * 2);        // 1 MB
    float*          bias = (float*)(ws + (size_t)BATCH * NF * 2 + (size_t)NL * NF * 2);
    float*          part = (float*)(ws + (size_t)BATCH * NF * 2 + (size_t)NL * NF * 2 + NL * 4);

    convert_kernel<<<(BATCH * NF) / (256 * 8), 256, 0, stream>>>(X, Xb);
    softmax_kernel<<<NL, 256, 0, stream>>>(logits, Wb, bias);
    gemm_lse_kernel<<<(BATCH / 128) * (NL / 128), 256, 0, stream>>>(Xb, Wb, bias, part);
    combine_kernel<<<BATCH / 256, 256, 0, stream>>>(part, out);
}